// Round 2
// baseline (690.983 us; speedup 1.0000x reference)
//
#include <hip/hip_runtime.h>

// Problem: bilinear texture lookup, texture [1024,1024,17] f32 (HWC), uv [N,2] f32.
// Outputs flat: values (N*16) || homogeneous (N*1) || vnn (N*17).
//
// Strategy: counting-sort points by 8x8 texel tile so texture reads are
// L1/L2-resident, then process in sorted order (scattered output writes).
#define TEX_H 1024
#define TEX_W 1024
#define TEX_C 17
#define TILE_SHIFT 3
#define TILES_X (TEX_W >> TILE_SHIFT)   // 128
#define TILES_Y (TEX_H >> TILE_SHIFT)   // 128
#define NTILES (TILES_X * TILES_Y)      // 16384

__device__ __forceinline__ void decode_uv(float2 p, int& x0, int& y0,
                                          float& fx, float& fy) {
    float x = p.x * (float)(TEX_W - 1);
    float y = p.y * (float)(TEX_H - 1);
    float x0f = fminf(fmaxf(floorf(x), 0.0f), (float)(TEX_W - 2));
    float y0f = fminf(fmaxf(floorf(y), 0.0f), (float)(TEX_H - 2));
    x0 = (int)x0f;
    y0 = (int)y0f;
    fx = x - x0f;
    fy = y - y0f;
}

__global__ __launch_bounds__(256) void k_zero(unsigned int* __restrict__ cursor) {
    int i = blockIdx.x * blockDim.x + threadIdx.x;
    if (i < NTILES) cursor[i] = 0u;
}

__global__ __launch_bounds__(256) void k_hist(const float* __restrict__ uv,
                                              unsigned int* __restrict__ cursor,
                                              int n) {
    int i = blockIdx.x * blockDim.x + threadIdx.x;
    if (i >= n) return;
    float2 p = ((const float2*)uv)[i];
    int x0, y0; float fx, fy;
    decode_uv(p, x0, y0, fx, fy);
    int tile = (y0 >> TILE_SHIFT) * TILES_X + (x0 >> TILE_SHIFT);
    atomicAdd(&cursor[tile], 1u);
}

// Single-block exclusive scan over NTILES bins, in place (counts -> start offsets).
__global__ __launch_bounds__(256) void k_scan(unsigned int* __restrict__ cursor) {
    __shared__ unsigned int part[256];
    __shared__ unsigned int excl[256];
    int t = threadIdx.x;
    const int per = NTILES / 256;  // 64
    unsigned int sum = 0;
    for (int k = 0; k < per; ++k) sum += cursor[t * per + k];
    part[t] = sum;
    __syncthreads();
    if (t == 0) {
        unsigned int run = 0;
        for (int j = 0; j < 256; ++j) { excl[j] = run; run += part[j]; }
    }
    __syncthreads();
    unsigned int run = excl[t];
    for (int k = 0; k < per; ++k) {
        unsigned int c = cursor[t * per + k];
        cursor[t * per + k] = run;
        run += c;
    }
}

__global__ __launch_bounds__(256) void k_scatter(const float* __restrict__ uv,
                                                 unsigned int* __restrict__ cursor,
                                                 uint4* __restrict__ records,
                                                 int n) {
    int i = blockIdx.x * blockDim.x + threadIdx.x;
    if (i >= n) return;
    float2 p = ((const float2*)uv)[i];
    int x0, y0; float fx, fy;
    decode_uv(p, x0, y0, fx, fy);
    int tile = (y0 >> TILE_SHIFT) * TILES_X + (x0 >> TILE_SHIFT);
    unsigned int pos = atomicAdd(&cursor[tile], 1u);
    uint4 rec;
    rec.x = (unsigned int)i;
    rec.y = (unsigned int)(y0 * TEX_W + x0);   // texel base index
    rec.z = __float_as_uint(fx);
    rec.w = __float_as_uint(fy);
    records[pos] = rec;
}

__global__ __launch_bounds__(256) void k_process(const float* __restrict__ tex,
                                                 const uint4* __restrict__ records,
                                                 float* __restrict__ out,
                                                 int n) {
    int g = blockIdx.x * blockDim.x + threadIdx.x;
    if (g >= n) return;
    uint4 rec = records[g];
    unsigned int idx = rec.x;
    float fx = __uint_as_float(rec.z);
    float fy = __uint_as_float(rec.w);
    float gx = 1.0f - fx;
    float gy = 1.0f - fy;

    const float* r0 = tex + (size_t)rec.y * TEX_C;
    const float* r1 = r0 + (size_t)TEX_W * TEX_C;

    float vnn[TEX_C];
#pragma unroll
    for (int c = 0; c < TEX_C; ++c) {
        float t00 = r0[c];
        float t01 = r0[c + TEX_C];
        float t10 = r1[c];
        float t11 = r1[c + TEX_C];
        float top = t00 * gx + t01 * fx;
        float bot = t10 * gx + t11 * fx;
        vnn[c] = top * gy + bot * fy;
    }

    float h = vnn[16];
    float inv = 1.0f / (h + 1e-5f);

    float4* vrow = (float4*)(out + (size_t)idx * 16);
#pragma unroll
    for (int q = 0; q < 4; ++q) {
        float4 v;
        v.x = vnn[q * 4 + 0] * inv;
        v.y = vnn[q * 4 + 1] * inv;
        v.z = vnn[q * 4 + 2] * inv;
        v.w = vnn[q * 4 + 3] * inv;
        vrow[q] = v;
    }

    out[(size_t)n * 16 + idx] = h;

    float* vout = out + (size_t)n * 17 + (size_t)idx * 17;
#pragma unroll
    for (int c = 0; c < TEX_C; ++c) vout[c] = vnn[c];
}

// Fallback (round-1 kernel): direct, unsorted — used if ws_size is too small.
__global__ __launch_bounds__(256) void k_direct(const float* __restrict__ tex,
                                                const float* __restrict__ uv,
                                                float* __restrict__ out,
                                                int n) {
    int i = blockIdx.x * blockDim.x + threadIdx.x;
    if (i >= n) return;
    float2 p = ((const float2*)uv)[i];
    int x0, y0; float fx, fy;
    decode_uv(p, x0, y0, fx, fy);
    float gx = 1.0f - fx;
    float gy = 1.0f - fy;
    const float* r0 = tex + ((size_t)y0 * TEX_W + (size_t)x0) * TEX_C;
    const float* r1 = r0 + (size_t)TEX_W * TEX_C;
    float vnn[TEX_C];
#pragma unroll
    for (int c = 0; c < TEX_C; ++c) {
        float t00 = r0[c];
        float t01 = r0[c + TEX_C];
        float t10 = r1[c];
        float t11 = r1[c + TEX_C];
        vnn[c] = (t00 * gx + t01 * fx) * gy + (t10 * gx + t11 * fx) * fy;
    }
    float h = vnn[16];
    float inv = 1.0f / (h + 1e-5f);
    float4* vrow = (float4*)(out + (size_t)i * 16);
#pragma unroll
    for (int q = 0; q < 4; ++q) {
        float4 v;
        v.x = vnn[q * 4 + 0] * inv;
        v.y = vnn[q * 4 + 1] * inv;
        v.z = vnn[q * 4 + 2] * inv;
        v.w = vnn[q * 4 + 3] * inv;
        vrow[q] = v;
    }
    out[(size_t)n * 16 + i] = h;
    float* vout = out + (size_t)n * 17 + (size_t)i * 17;
#pragma unroll
    for (int c = 0; c < TEX_C; ++c) vout[c] = vnn[c];
}

extern "C" void kernel_launch(void* const* d_in, const int* in_sizes, int n_in,
                              void* d_out, int out_size, void* d_ws, size_t ws_size,
                              hipStream_t stream) {
    const float* tex = (const float*)d_in[0];
    const float* uv  = (const float*)d_in[1];
    float* out = (float*)d_out;
    int n = in_sizes[1] / 2;

    const int block = 256;
    const int gridN = (n + block - 1) / block;

    size_t need = (size_t)NTILES * 4 + (size_t)n * 16;
    if (ws_size < need) {
        k_direct<<<gridN, block, 0, stream>>>(tex, uv, out, n);
        return;
    }

    unsigned int* cursor = (unsigned int*)d_ws;
    uint4* records = (uint4*)((char*)d_ws + (size_t)NTILES * 4);

    k_zero<<<(NTILES + block - 1) / block, block, 0, stream>>>(cursor);
    k_hist<<<gridN, block, 0, stream>>>(uv, cursor, n);
    k_scan<<<1, block, 0, stream>>>(cursor);
    k_scatter<<<gridN, block, 0, stream>>>(uv, cursor, records, n);
    k_process<<<gridN, block, 0, stream>>>(tex, records, out, n);
}